// Round 6
// baseline (249.282 us; speedup 1.0000x reference)
//
#include <hip/hip_runtime.h>

typedef __bf16 bf16;
typedef __bf16 bf16x2 __attribute__((ext_vector_type(2)));
typedef __bf16 bf16x4 __attribute__((ext_vector_type(4)));
typedef __bf16 bf16x8 __attribute__((ext_vector_type(8)));
typedef float f32x4 __attribute__((ext_vector_type(4)));

#define TT_ 2048
#define CC_ 1024
#define HH_ 64

// scale * 1/ln(2): softmax via exp2, no max subtraction (|s|<~3, fp32-safe).
// Folded into q at projection time (qb is pre-scaled by qkv_kernel).
#define SCALE2 0.045084221f

static __device__ __forceinline__ unsigned pack_bf16(float a, float b) {
    union { bf16x2 h; unsigned u; } z;
    z.h = bf16x2{(bf16)a, (bf16)b};
    return z.u;
}
// v_permlane32_swap_b32: a' = [a.lo32 | b.lo32], b' = [a.hi32 | b.hi32]
static __device__ __forceinline__ void plswap32(unsigned &a, unsigned &b) {
    asm("v_permlane32_swap_b32 %0, %1" : "+v"(a), "+v"(b));
}
// v_permlane16_swap_b32: odd 16-rows of a swap with even 16-rows of b
static __device__ __forceinline__ void plswap16(unsigned &a, unsigned &b) {
    asm("v_permlane16_swap_b32 %0, %1" : "+v"(a), "+v"(b));
}

// ---------------- prep: Wt[m][n][k] = W_m[k][n], fp32 -> bf16, LDS transpose --
__global__ __launch_bounds__(256) void prep_w(const float* __restrict__ Wq,
                                              const float* __restrict__ Wk,
                                              const float* __restrict__ Wv,
                                              bf16* __restrict__ Wt) {
    __shared__ bf16 Ls[64 * 65];
    const int m  = blockIdx.x >> 4;
    const int k0 = (blockIdx.x & 15) * 64;
    const float* W = (m == 0) ? Wq : (m == 1) ? Wk : Wv;
    const int tid = threadIdx.x;
    #pragma unroll
    for (int j = 0; j < 4; ++j) {
        int idx = tid + 256 * j;
        int r   = idx >> 4;
        int c4  = (idx & 15) * 4;
        float4 w = *(const float4*)&W[(size_t)(k0 + r) * HH_ + c4];
        Ls[r * 65 + c4 + 0] = (bf16)w.x;
        Ls[r * 65 + c4 + 1] = (bf16)w.y;
        Ls[r * 65 + c4 + 2] = (bf16)w.z;
        Ls[r * 65 + c4 + 3] = (bf16)w.w;
    }
    __syncthreads();
    #pragma unroll
    for (int j = 0; j < 4; ++j) {
        int idx = tid + 256 * j;
        int n   = idx >> 4;
        int kc  = (idx & 15) * 4;
        bf16x4 v;
        #pragma unroll
        for (int i = 0; i < 4; ++i) v[i] = Ls[(kc + i) * 65 + n];
        *(bf16x4*)&Wt[m * 65536 + n * 1024 + k0 + kc] = v;
    }
}

// ---------------- fused QKV projection ---------------------------------------
// Round 6: occupancy play. 32-row tiles -> grid 1024 = 4 blocks/CU =
// 16 waves/CU (was 8). Prefetch machinery dropped (rounds 3-4: neutral) to
// fit the 128-VGPR cap of __launch_bounds__(256,4); TLP now hides latency.
// q output PRE-SCALED by SCALE2 (softmax scale/ln2).
__global__ __launch_bounds__(256, 4) void qkv_kernel(const float* __restrict__ x,
                                                     const bf16* __restrict__ Wt,
                                                     bf16* __restrict__ qb,
                                                     bf16* __restrict__ kb,
                                                     bf16* __restrict__ vt) {
    __shared__ __align__(16) bf16 Xs[2][32 * 72];
    const int tid  = threadIdx.x;
    const int wave = tid >> 6;
    const int lane = tid & 15;
    const int quad = (tid & 63) >> 4;
    const int m0   = blockIdx.x * 32;

    f32x4 acc[2][3];
    #pragma unroll
    for (int i = 0; i < 2; ++i)
        #pragma unroll
        for (int j = 0; j < 3; ++j) acc[i][j] = f32x4{0.f, 0.f, 0.f, 0.f};

    // staging: thread owns row srow, 8 consecutive floats at sc8
    const int srow = tid >> 3;
    const int sc8  = (tid & 7) * 8;

    float4 xr0 = *(const float4*)&x[(size_t)(m0 + srow) * CC_ + sc8];
    float4 xr1 = *(const float4*)&x[(size_t)(m0 + srow) * CC_ + sc8 + 4];
    {
        bf16x8 bv = {(bf16)xr0.x, (bf16)xr0.y, (bf16)xr0.z, (bf16)xr0.w,
                     (bf16)xr1.x, (bf16)xr1.y, (bf16)xr1.z, (bf16)xr1.w};
        *(bf16x8*)&Xs[0][srow * 72 + sc8] = bv;
    }

    for (int kbi = 0; kbi < 16; ++kbi) {
        const int cur = kbi & 1;
        const int k0  = kbi * 64;
        __syncthreads();
        if (kbi < 15) {
            xr0 = *(const float4*)&x[(size_t)(m0 + srow) * CC_ + k0 + 64 + sc8];
            xr1 = *(const float4*)&x[(size_t)(m0 + srow) * CC_ + k0 + 64 + sc8 + 4];
        }
        bf16x8 bfr[2][3];
        #pragma unroll
        for (int step = 0; step < 2; ++step)
            #pragma unroll
            for (int ct = 0; ct < 3; ++ct)
                bfr[step][ct] = *(const bf16x8*)&Wt[(size_t)(wave * 48 + ct * 16 + lane) * 1024 + k0 + step * 32 + quad * 8];
        bf16x8 afr[2][2];
        #pragma unroll
        for (int step = 0; step < 2; ++step)
            #pragma unroll
            for (int rt = 0; rt < 2; ++rt)
                afr[step][rt] = *(const bf16x8*)&Xs[cur][(rt * 16 + lane) * 72 + step * 32 + quad * 8];
        #pragma unroll
        for (int step = 0; step < 2; ++step)
            #pragma unroll
            for (int ct = 0; ct < 3; ++ct)
                #pragma unroll
                for (int rt = 0; rt < 2; ++rt)
                    acc[rt][ct] = __builtin_amdgcn_mfma_f32_16x16x32_bf16(afr[step][rt], bfr[step][ct], acc[rt][ct], 0, 0, 0);
        if (kbi < 15) {
            bf16x8 bv = {(bf16)xr0.x, (bf16)xr0.y, (bf16)xr0.z, (bf16)xr0.w,
                         (bf16)xr1.x, (bf16)xr1.y, (bf16)xr1.z, (bf16)xr1.w};
            *(bf16x8*)&Xs[cur ^ 1][srow * 72 + sc8] = bv;
        }
    }

    // epilogue: C/D layout col=lane, row=quad*4+r
    const int bb = m0 >> 11;
    const int t0 = m0 & 2047;
    __syncthreads();
    #pragma unroll
    for (int ct = 0; ct < 3; ++ct) {
        int c0 = wave * 48 + ct * 16;
        if (c0 < 64) {                          // q: pre-scaled by SCALE2
            int h = c0 + lane;
            #pragma unroll
            for (int rt = 0; rt < 2; ++rt)
                #pragma unroll
                for (int r = 0; r < 4; ++r)
                    qb[(size_t)(m0 + rt * 16 + quad * 4 + r) * HH_ + h] = (bf16)(acc[rt][ct][r] * SCALE2);
        } else if (c0 < 128) {                  // k
            int h = (c0 - 64) + lane;
            #pragma unroll
            for (int rt = 0; rt < 2; ++rt)
                #pragma unroll
                for (int r = 0; r < 4; ++r)
                    kb[(size_t)(m0 + rt * 16 + quad * 4 + r) * HH_ + h] = (bf16)acc[rt][ct][r];
        } else {                                // v -> LDS for transpose
            int h = (c0 - 128) + lane;
            #pragma unroll
            for (int rt = 0; rt < 2; ++rt)
                #pragma unroll
                for (int r = 0; r < 4; ++r)
                    Xs[0][(rt * 16 + quad * 4 + r) * 72 + h] = (bf16)acc[rt][ct][r];
        }
    }
    __syncthreads();
    {
        int h  = tid >> 2;
        int tc = (tid & 3) * 8;
        bf16x8 v0;
        #pragma unroll
        for (int i = 0; i < 8; ++i) v0[i] = Xs[0][(tc + i) * 72 + h];
        *(bf16x8*)&vt[(size_t)bb * HH_ * TT_ + (size_t)h * TT_ + t0 + tc] = v0;
    }
}

// ---------------- flash attention, non-split, direct output ------------------
// Round 6: 512-thread blocks, 8 waves = 4 q-waves x 2 k-groups. k-group kg
// handles windows {kg, kg+2} of each chunk; K/V staging shared by both
// groups (no traffic increase). Grid 512 = 2 blocks/CU = 16 waves/CU
// (was 8) -- doubles the independent serial chains per SIMD. Epilogue:
// kg=1 dumps o/l partials to LDS (reusing Ks, stride 65), kg=0 reduces,
// normalizes (rowsum via ones-MFMA, same register layout), writes fp32 out.
__global__ __launch_bounds__(512, 4) void attn_kernel(const bf16* __restrict__ qb,
                                                      const bf16* __restrict__ kb,
                                                      const bf16* __restrict__ vt,
                                                      float* __restrict__ out) {
    __shared__ __align__(16) bf16 Ks[128 * 72];
    __shared__ __align__(16) bf16 Vs[64 * 136];

    const int tid  = threadIdx.x;
    const int wave = tid >> 6;        // 0..7
    const int qw   = wave & 3;        // q-wave
    const int kg   = wave >> 2;       // k-group
    const int lane = tid & 15;
    const int quad = (tid & 63) >> 4;

    const int jb = blockIdx.x;
    const int bb = jb & 15;
    const int p  = jb >> 4;
    const int qi = (p < 16) ? p : 47 - p;
    const int nch = (qi >> 1) + 1;          // chunks of 128 keys, incl. diag

    const int qrow  = qi * 64 + qw * 16;
    const int qg    = qrow + lane;          // this lane's q row
    const int qmaxw = qrow + 15;            // max q row in this wave

    // staging (512 threads): K 128x64 and V^T 64x128, 2 bf16x8 each
    const int krow = tid >> 3, kc8 = (tid & 7) * 8;       // rows 0..63 (+64)
    const int vh   = tid >> 4, vc8 = (tid & 15) * 8;      // h 0..31 (+32)
    const bf16* kp = kb + (size_t)(bb * TT_ + krow) * HH_ + kc8;
    const bf16* vp = vt + (size_t)bb * HH_ * TT_ + (size_t)vh * TT_ + vc8;

    // prologue: issue chunk-0 loads
    bf16x8 kr[2], vvr[2];
    #pragma unroll
    for (int jj = 0; jj < 2; ++jj) kr[jj]  = *(const bf16x8*)&kp[(size_t)jj * 64 * HH_];
    #pragma unroll
    for (int jj = 0; jj < 2; ++jj) vvr[jj] = *(const bf16x8*)&vp[jj * 32 * TT_];

    // Q fragment (B operand): lane -> q col, quad*8 -> h  (pre-scaled)
    bf16x8 aq[2];
    #pragma unroll
    for (int step = 0; step < 2; ++step)
        aq[step] = *(const bf16x8*)&qb[(size_t)(bb * TT_ + qg) * HH_ + step * 32 + quad * 8];

    // all-ones B fragment for the row-sum MFMA
    bf16x8 vones;
    #pragma unroll
    for (int i = 0; i < 8; ++i) vones[i] = (bf16)1.0f;

    f32x4 o_acc[4];
    #pragma unroll
    for (int ht = 0; ht < 4; ++ht) o_acc[ht] = f32x4{0.f, 0.f, 0.f, 0.f};
    f32x4 lacc = f32x4{0.f, 0.f, 0.f, 0.f};

    for (int c = 0; c < nch; ++c) {
        const int s0 = c * 128;
        __syncthreads();                 // all waves done computing chunk c-1
        #pragma unroll
        for (int jj = 0; jj < 2; ++jj) *(bf16x8*)&Ks[(krow + 64 * jj) * 72 + kc8] = kr[jj];
        #pragma unroll
        for (int jj = 0; jj < 2; ++jj) *(bf16x8*)&Vs[(vh + 32 * jj) * 136 + vc8]  = vvr[jj];
        __syncthreads();
        if (c + 1 < nch) {               // issue next chunk's loads early
            #pragma unroll
            for (int jj = 0; jj < 2; ++jj)
                kr[jj] = *(const bf16x8*)&kp[(size_t)((c + 1) * 128 + jj * 64) * HH_];
            #pragma unroll
            for (int jj = 0; jj < 2; ++jj)
                vvr[jj] = *(const bf16x8*)&vp[(c + 1) * 128 + jj * 32 * TT_];
        }

        const bool msk = (c == nch - 1);
        #pragma unroll
        for (int wi = 0; wi < 2; ++wi) {    // this k-group's 2 windows
            const int w = kg + wi * 2;
            if (msk && (s0 + w * 32 > qmaxw)) continue;       // wave-uniform
            const bool haveB = !msk || (s0 + w * 32 + 16 <= qmaxw);

            // QK^T (swapped): s[key=tile+quad*4+r][q=qg]
            f32x4 sA = {0.f, 0.f, 0.f, 0.f};
            f32x4 sB = {0.f, 0.f, 0.f, 0.f};
            __builtin_amdgcn_s_setprio(1);
            {
                bf16x8 ak0 = *(const bf16x8*)&Ks[(w * 32 + lane) * 72 + quad * 8];
                bf16x8 ak1 = *(const bf16x8*)&Ks[(w * 32 + lane) * 72 + 32 + quad * 8];
                sA = __builtin_amdgcn_mfma_f32_16x16x32_bf16(ak0, aq[0], sA, 0, 0, 0);
                sA = __builtin_amdgcn_mfma_f32_16x16x32_bf16(ak1, aq[1], sA, 0, 0, 0);
            }
            if (haveB) {
                bf16x8 bk0 = *(const bf16x8*)&Ks[(w * 32 + 16 + lane) * 72 + quad * 8];
                bf16x8 bk1 = *(const bf16x8*)&Ks[(w * 32 + 16 + lane) * 72 + 32 + quad * 8];
                sB = __builtin_amdgcn_mfma_f32_16x16x32_bf16(bk0, aq[0], sB, 0, 0, 0);
                sB = __builtin_amdgcn_mfma_f32_16x16x32_bf16(bk1, aq[1], sB, 0, 0, 0);
            }
            __builtin_amdgcn_s_setprio(0);

            // softmax (in-register, max-free; scale pre-folded into q)
            const int kA0 = s0 + w * 32 + quad * 4;
            float eA[4], eB[4];
            #pragma unroll
            for (int r = 0; r < 4; ++r) {
                float e = __builtin_amdgcn_exp2f(sA[r]);
                if (msk && (kA0 + r > qg)) e = 0.f;
                eA[r] = e;
            }
            if (haveB) {
                #pragma unroll
                for (int r = 0; r < 4; ++r) {
                    float e = __builtin_amdgcn_exp2f(sB[r]);
                    if (msk && (kA0 + 16 + r > qg)) e = 0.f;
                    eB[r] = e;
                }
            } else {
                #pragma unroll
                for (int r = 0; r < 4; ++r) eB[r] = 0.f;
            }

            // P: C-layout -> 16x16x32 A-layout, all in registers
            unsigned d0 = pack_bf16(eA[0], eA[1]);
            unsigned d1 = pack_bf16(eA[2], eA[3]);
            unsigned d2 = pack_bf16(eB[0], eB[1]);
            unsigned d3 = pack_bf16(eB[2], eB[3]);
            plswap32(d0, d2);
            plswap16(d0, d2);
            plswap32(d1, d3);
            plswap16(d1, d3);
            union { unsigned u[4]; bf16x8 v; } apu;
            apu.u[0] = d0; apu.u[1] = d1; apu.u[2] = d2; apu.u[3] = d3;

            // PV + row-sum: x32 MFMA straight from registers + Vs
            __builtin_amdgcn_s_setprio(1);
            #pragma unroll
            for (int ht = 0; ht < 4; ++ht) {
                bf16x8 bv = *(const bf16x8*)&Vs[(ht * 16 + lane) * 136 + w * 32 + quad * 8];
                o_acc[ht] = __builtin_amdgcn_mfma_f32_16x16x32_bf16(apu.v, bv, o_acc[ht], 0, 0, 0);
            }
            lacc = __builtin_amdgcn_mfma_f32_16x16x32_bf16(apu.v, vones, lacc, 0, 0, 0);
            __builtin_amdgcn_s_setprio(0);
        }
    }

    // ---- cross-k-group combine (reuse Ks as fp32 buffer, stride 65) ----
    __syncthreads();
    float* cbuf = (float*)Ks;             // [64][65] fp32 = 16.6 KB
    float* lbuf = cbuf + 64 * 65;         // 64 fp32
    if (kg == 1) {
        #pragma unroll
        for (int ht = 0; ht < 4; ++ht)
            #pragma unroll
            for (int r = 0; r < 4; ++r)
                cbuf[(qw * 16 + quad * 4 + r) * 65 + ht * 16 + lane] = o_acc[ht][r];
        if (lane == 0) {
            #pragma unroll
            for (int r = 0; r < 4; ++r) lbuf[qw * 16 + quad * 4 + r] = lacc[r];
        }
    }
    __syncthreads();
    if (kg == 0) {
        #pragma unroll
        for (int ht = 0; ht < 4; ++ht)
            #pragma unroll
            for (int r = 0; r < 4; ++r)
                o_acc[ht][r] += cbuf[(qw * 16 + quad * 4 + r) * 65 + ht * 16 + lane];
        float inv[4];
        #pragma unroll
        for (int r = 0; r < 4; ++r)
            inv[r] = __builtin_amdgcn_rcpf(lacc[r] + lbuf[qw * 16 + quad * 4 + r]);
        #pragma unroll
        for (int ht = 0; ht < 4; ++ht)
            #pragma unroll
            for (int r = 0; r < 4; ++r)
                out[(size_t)(bb * TT_ + qrow + quad * 4 + r) * HH_ + ht * 16 + lane] = o_acc[ht][r] * inv[r];
    }
}

extern "C" void kernel_launch(void* const* d_in, const int* in_sizes, int n_in,
                              void* d_out, int out_size, void* d_ws, size_t ws_size,
                              hipStream_t stream) {
    const float* x  = (const float*)d_in[0];
    const float* Wq = (const float*)d_in[1];
    const float* Wk = (const float*)d_in[2];
    const float* Wv = (const float*)d_in[3];
    float* out = (float*)d_out;

    char* ws = (char*)d_ws;
    bf16*  qb = (bf16*)(ws);                       // 4 MiB (pre-scaled q)
    bf16*  kb = (bf16*)(ws + 4194304);             // 4 MiB
    bf16*  vt = (bf16*)(ws + 8388608);             // 4 MiB  V^T [bb][h][t]
    bf16*  Wt = (bf16*)(ws + 12582912);            // 384 KiB

    prep_w<<<48, 256, 0, stream>>>(Wq, Wk, Wv, Wt);
    qkv_kernel<<<1024, 256, 0, stream>>>(x, Wt, qb, kb, vt);
    attn_kernel<<<512, 512, 0, stream>>>(qb, kb, vt, out);
}